// Round 7
// baseline (181.732 us; speedup 1.0000x reference)
//
#include <hip/hip_runtime.h>

#define N_NODES 50000
#define HIDDEN  128
#define N_EDGES 600000
#define BR      32                        // rows per tile in fused kernel
#define NB      ((N_NODES + 255) / 256)   // 196 scan blocks
#define NTILES  ((N_NODES + BR - 1) / BR) // 1563

typedef __attribute__((ext_vector_type(8))) short short8v;
typedef __attribute__((ext_vector_type(4))) float f32x4;

// ---------------- threefry2x32 (JAX-exact, key = (0,42)) ----------------
__device__ __forceinline__ unsigned rotl32(unsigned v, int r) {
  return (v << r) | (v >> (32 - r));
}

__device__ __forceinline__ void threefry2x32(unsigned x0, unsigned x1,
                                             unsigned& o0, unsigned& o1) {
  const unsigned ks0 = 0u, ks1 = 42u;
  const unsigned ks2 = ks0 ^ ks1 ^ 0x1BD11BDAu;
  const unsigned ks[3] = {ks0, ks1, ks2};
  const int rot[2][4] = {{13, 15, 26, 6}, {17, 29, 16, 24}};
  x0 += ks0; x1 += ks1;
#pragma unroll
  for (int i = 0; i < 5; ++i) {
#pragma unroll
    for (int j = 0; j < 4; ++j) {
      x0 += x1;
      x1 = rotl32(x1, rot[i & 1][j]);
      x1 ^= x0;
    }
    x0 += ks[(i + 1) % 3];
    x1 += ks[(i + 2) % 3] + (unsigned)(i + 1);
  }
  o0 = x0; o1 = x1;
}

// JAX threefry_partitionable random_bits: bits[c] = o0^o1 of
// threefry(key=(0,42), counter=(0,c)); uniform = ((bits>>9)|0x3f800000)-1.
__device__ __forceinline__ float col_mask(int c) {
  unsigned o0, o1;
  threefry2x32(0u, (unsigned)c, o0, o1);
  unsigned bits = o0 ^ o1;
  float u = __uint_as_float((bits >> 9) | 0x3f800000u) - 1.0f;
  return (u < 0.75f) ? 1.0f : 0.0f;
}

__device__ __forceinline__ unsigned short f2bf(float f) {
  unsigned u = __float_as_uint(f);
  u += 0x7fffu + ((u >> 16) & 1u);  // round-to-nearest-even
  return (unsigned short)(u >> 16);
}

__device__ __forceinline__ float bflo(unsigned u) {
  return __uint_as_float(u << 16);
}
__device__ __forceinline__ float bfhi(unsigned u) {
  return __uint_as_float(u & 0xffff0000u);
}

__device__ __forceinline__ float rlane(float v, int l) {
  return __int_as_float(__builtin_amdgcn_readlane(__float_as_int(v), l));
}

// ---------------- prep: hist(dst) + xb = bf16(mask .* x) + Wt = bf16(W^T) --
// 3125 blocks x 256 threads; thread handles 8 xb elements; gid<N_EDGES also
// histograms; gid<4096 also transposes 4 elements of each W.
__global__ __launch_bounds__(256) void prep_kernel(
    const float* __restrict__ x, const float* __restrict__ W1,
    const float* __restrict__ W2, const int* __restrict__ ei,
    unsigned short* __restrict__ xb, unsigned short* __restrict__ Wt1,
    unsigned short* __restrict__ Wt2, int* __restrict__ deg) {
  __shared__ float msk[HIDDEN];
  if (threadIdx.x < HIDDEN) msk[threadIdx.x] = col_mask(threadIdx.x);
  __syncthreads();

  const int gid = blockIdx.x * 256 + threadIdx.x;
  const int e0 = gid * 8;  // 8 contiguous elements
  if (e0 < N_NODES * HIDDEN) {
    const int c0 = e0 & (HIDDEN - 1);
    const float4 v0 = *reinterpret_cast<const float4*>(x + e0);
    const float4 v1 = *reinterpret_cast<const float4*>(x + e0 + 4);
    unsigned short h[8];
    h[0] = f2bf(v0.x * msk[c0 + 0]);
    h[1] = f2bf(v0.y * msk[c0 + 1]);
    h[2] = f2bf(v0.z * msk[c0 + 2]);
    h[3] = f2bf(v0.w * msk[c0 + 3]);
    h[4] = f2bf(v1.x * msk[c0 + 4]);
    h[5] = f2bf(v1.y * msk[c0 + 5]);
    h[6] = f2bf(v1.z * msk[c0 + 6]);
    h[7] = f2bf(v1.w * msk[c0 + 7]);
    *reinterpret_cast<uint4*>(xb + e0) = *reinterpret_cast<uint4*>(h);
  }
  if (gid < N_EDGES) atomicAdd(deg + ei[N_EDGES + gid], 1);
  if (gid < HIDDEN * HIDDEN / 4) {
#pragma unroll
    for (int i = 0; i < 4; ++i) {
      int t = gid * 4 + i;            // Wt index
      int col = t >> 7, k = t & 127;  // Wt[col][k] = W[k][col]
      Wt1[t] = f2bf(W1[k * HIDDEN + col]);
      Wt2[t] = f2bf(W2[k * HIDDEN + col]);
    }
  }
}

// ---------------- two-level scan ----------------
__global__ __launch_bounds__(256) void scanA_kernel(const int* __restrict__ deg,
                                                    int* __restrict__ bsum) {
  int idx = blockIdx.x * 256 + threadIdx.x;
  int v = (idx < N_NODES) ? deg[idx] : 0;
#pragma unroll
  for (int off = 32; off; off >>= 1) v += __shfl_down(v, off, 64);
  __shared__ int ws4[4];
  if ((threadIdx.x & 63) == 0) ws4[threadIdx.x >> 6] = v;
  __syncthreads();
  if (threadIdx.x == 0) bsum[blockIdx.x] = ws4[0] + ws4[1] + ws4[2] + ws4[3];
}

__global__ __launch_bounds__(256) void scanB_kernel(const int* __restrict__ bsum,
                                                    int* __restrict__ bpre,
                                                    int* __restrict__ offs,
                                                    int* __restrict__ ticket) {
  __shared__ int s[256];
  const int t = threadIdx.x;
  int v = (t < NB) ? bsum[t] : 0;
  s[t] = v;
  __syncthreads();
  int acc = v;
  for (int off = 1; off < 256; off <<= 1) {
    int add = (t >= off) ? s[t - off] : 0;
    __syncthreads();
    acc += add;
    s[t] = acc;
    __syncthreads();
  }
  if (t < NB) bpre[t] = acc - v;  // exclusive prefix
  if (t == 0) offs[N_NODES] = N_EDGES;
  if (t == 100) *ticket = 0;  // reset work-stealing ticket each call
}

__global__ __launch_bounds__(256) void scanC_kernel(const int* __restrict__ deg,
                                                    const int* __restrict__ bpre,
                                                    int* __restrict__ offs,
                                                    int* __restrict__ pos) {
  __shared__ int s[256];
  const int t = threadIdx.x;
  const int idx = blockIdx.x * 256 + t;
  int v = (idx < N_NODES) ? deg[idx] : 0;
  s[t] = v;
  __syncthreads();
  int acc = v;
  for (int off = 1; off < 256; off <<= 1) {
    int add = (t >= off) ? s[t - off] : 0;
    __syncthreads();
    acc += add;
    s[t] = acc;
    __syncthreads();
  }
  if (idx < N_NODES) {
    int o = bpre[blockIdx.x] + acc - v;
    offs[idx] = o;
    pos[idx] = o;
  }
}

__global__ __launch_bounds__(256) void fill_kernel(const int* __restrict__ ei,
                                                   int* __restrict__ pos,
                                                   int* __restrict__ csr) {
  int e = blockIdx.x * blockDim.x + threadIdx.x;
  if (e >= N_EDGES) return;
  int src = ei[e];
  int dst = ei[N_EDGES + e];
  int p = atomicAdd(pos + dst, 1);
  csr[p] = src;
}

// ---------------- fused gather(bf16) + MLP (bf16 MFMA), persistent ---------
// Persistent blocks grab 32-row tiles via a global ticket. Wave w gathers
// rows [8w,8w+8) from xb into H1 (XOR-swizzled LDS), then computes output
// cols [32w, 32w+32). 8-deep load unroll; csr indices via scalar loads.
__global__ __launch_bounds__(256) void fused_xb_kernel(
    const int* __restrict__ offs, const int* __restrict__ csr,
    const unsigned short* __restrict__ xb,
    const unsigned short* __restrict__ Wt1,
    const unsigned short* __restrict__ Wt2, const float* __restrict__ b1,
    const float* __restrict__ b2, int* __restrict__ ticket,
    float* __restrict__ out) {
  __shared__ unsigned short H1[BR * HIDDEN];  // 8 KB, swizzled
  __shared__ unsigned short H2[BR * HIDDEN];  // 8 KB, swizzled
  __shared__ int s_tile;

  const int tid = threadIdx.x;
  const int lane = tid & 63;
  const int wave = tid >> 6;
  const int c0 = lane * 2;
  const int colbase = wave * 32;  // 2 col-tiles per wave

  float bias1[2], bias2[2];
#pragma unroll
  for (int c = 0; c < 2; ++c) {
    bias1[c] = b1[colbase + c * 16 + (lane & 15)];
    bias2[c] = b2[colbase + c * 16 + (lane & 15)];
  }

  for (;;) {
    __syncthreads();  // prev tile fully done (LDS + s_tile reuse safe)
    if (tid == 0) s_tile = atomicAdd(ticket, 1);
    __syncthreads();
    const int tile = s_tile;
    if (tile >= NTILES) break;
    const int base = tile * BR;

    // ---- phase 1: gather (mask baked into xb) -> H1 ----
#pragma unroll 1
    for (int i = 0; i < 8; ++i) {
      const int node = base + wave * 8 + i;
      float ax = 0.f, ay = 0.f;
      if (node < N_NODES) {
        unsigned own =
            *reinterpret_cast<const unsigned*>(xb + (size_t)node * HIDDEN + c0);
        ax = bflo(own);
        ay = bfhi(own);
        const int s = __builtin_amdgcn_readfirstlane(offs[node]);
        const int e = __builtin_amdgcn_readfirstlane(offs[node + 1]);
        int j = s;
        for (; j + 8 <= e; j += 8) {
          int n0 = csr[j],     n1 = csr[j + 1], n2 = csr[j + 2], n3 = csr[j + 3];
          int n4 = csr[j + 4], n5 = csr[j + 5], n6 = csr[j + 6], n7 = csr[j + 7];
          unsigned u0 = *reinterpret_cast<const unsigned*>(xb + (size_t)n0 * HIDDEN + c0);
          unsigned u1 = *reinterpret_cast<const unsigned*>(xb + (size_t)n1 * HIDDEN + c0);
          unsigned u2 = *reinterpret_cast<const unsigned*>(xb + (size_t)n2 * HIDDEN + c0);
          unsigned u3 = *reinterpret_cast<const unsigned*>(xb + (size_t)n3 * HIDDEN + c0);
          unsigned u4 = *reinterpret_cast<const unsigned*>(xb + (size_t)n4 * HIDDEN + c0);
          unsigned u5 = *reinterpret_cast<const unsigned*>(xb + (size_t)n5 * HIDDEN + c0);
          unsigned u6 = *reinterpret_cast<const unsigned*>(xb + (size_t)n6 * HIDDEN + c0);
          unsigned u7 = *reinterpret_cast<const unsigned*>(xb + (size_t)n7 * HIDDEN + c0);
          ax += bflo(u0) + bflo(u1) + bflo(u2) + bflo(u3) +
                bflo(u4) + bflo(u5) + bflo(u6) + bflo(u7);
          ay += bfhi(u0) + bfhi(u1) + bfhi(u2) + bfhi(u3) +
                bfhi(u4) + bfhi(u5) + bfhi(u6) + bfhi(u7);
        }
        for (; j + 4 <= e; j += 4) {
          int n0 = csr[j], n1 = csr[j + 1], n2 = csr[j + 2], n3 = csr[j + 3];
          unsigned u0 = *reinterpret_cast<const unsigned*>(xb + (size_t)n0 * HIDDEN + c0);
          unsigned u1 = *reinterpret_cast<const unsigned*>(xb + (size_t)n1 * HIDDEN + c0);
          unsigned u2 = *reinterpret_cast<const unsigned*>(xb + (size_t)n2 * HIDDEN + c0);
          unsigned u3 = *reinterpret_cast<const unsigned*>(xb + (size_t)n3 * HIDDEN + c0);
          ax += bflo(u0) + bflo(u1) + bflo(u2) + bflo(u3);
          ay += bfhi(u0) + bfhi(u1) + bfhi(u2) + bfhi(u3);
        }
        for (; j < e; ++j) {
          int nb = csr[j];
          unsigned u = *reinterpret_cast<const unsigned*>(xb + (size_t)nb * HIDDEN + c0);
          ax += bflo(u);
          ay += bfhi(u);
        }
      }
      const int row = wave * 8 + i;
      unsigned hx = (unsigned)f2bf(ax) | ((unsigned)f2bf(ay) << 16);
      const int byte = (row * 256 + c0 * 2) ^ ((row & 7) << 4);
      *reinterpret_cast<unsigned*>(reinterpret_cast<char*>(H1) + byte) = hx;
    }
    __syncthreads();

    // ---- phase 2: GEMM1 (H1 @ Wt1 + b1, relu) -> H2 ----
    f32x4 acc[2][2] = {};
#pragma unroll
    for (int kt = 0; kt < 4; ++kt) {
      short8v a[2], b[2];
#pragma unroll
      for (int r = 0; r < 2; ++r) {
        int row = r * 16 + (lane & 15);
        int byte = (row * 256 + kt * 64 + (lane >> 4) * 16) ^ ((row & 7) << 4);
        a[r] = *reinterpret_cast<const short8v*>(
            reinterpret_cast<const char*>(H1) + byte);
      }
#pragma unroll
      for (int c = 0; c < 2; ++c) {
        int col = colbase + c * 16 + (lane & 15);
        b[c] = *reinterpret_cast<const short8v*>(
            reinterpret_cast<const char*>(Wt1) + col * 256 + kt * 64 +
            (lane >> 4) * 16);
      }
#pragma unroll
      for (int r = 0; r < 2; ++r)
#pragma unroll
        for (int c = 0; c < 2; ++c)
          acc[r][c] = __builtin_amdgcn_mfma_f32_16x16x32_bf16(
              a[r], b[c], acc[r][c], 0, 0, 0);
    }
#pragma unroll
    for (int r = 0; r < 2; ++r)
#pragma unroll
      for (int c = 0; c < 2; ++c)
#pragma unroll
        for (int q = 0; q < 4; ++q) {
          int row = r * 16 + (lane >> 4) * 4 + q;
          int col = colbase + c * 16 + (lane & 15);
          float v = fmaxf(acc[r][c][q] + bias1[c], 0.f);
          int byte = (row * 256 + col * 2) ^ ((row & 7) << 4);
          *reinterpret_cast<unsigned short*>(reinterpret_cast<char*>(H2) +
                                             byte) = f2bf(v);
        }
    __syncthreads();

    // ---- phase 3: GEMM2 (H2 @ Wt2 + b2) -> out ----
    f32x4 acc2[2][2] = {};
#pragma unroll
    for (int kt = 0; kt < 4; ++kt) {
      short8v a[2], b[2];
#pragma unroll
      for (int r = 0; r < 2; ++r) {
        int row = r * 16 + (lane & 15);
        int byte = (row * 256 + kt * 64 + (lane >> 4) * 16) ^ ((row & 7) << 4);
        a[r] = *reinterpret_cast<const short8v*>(
            reinterpret_cast<const char*>(H2) + byte);
      }
#pragma unroll
      for (int c = 0; c < 2; ++c) {
        int col = colbase + c * 16 + (lane & 15);
        b[c] = *reinterpret_cast<const short8v*>(
            reinterpret_cast<const char*>(Wt2) + col * 256 + kt * 64 +
            (lane >> 4) * 16);
      }
#pragma unroll
      for (int r = 0; r < 2; ++r)
#pragma unroll
        for (int c = 0; c < 2; ++c)
          acc2[r][c] = __builtin_amdgcn_mfma_f32_16x16x32_bf16(
              a[r], b[c], acc2[r][c], 0, 0, 0);
    }
#pragma unroll
    for (int r = 0; r < 2; ++r)
#pragma unroll
      for (int c = 0; c < 2; ++c)
#pragma unroll
        for (int q = 0; q < 4; ++q) {
          int row = base + r * 16 + (lane >> 4) * 4 + q;
          if (row < N_NODES) {
            int col = colbase + c * 16 + (lane & 15);
            out[(size_t)row * HIDDEN + col] = acc2[r][c][q] + bias2[c];
          }
        }
  }
}

// ---------------- Tier-B/C fallback kernels (round-3 proven) ---------------
__global__ __launch_bounds__(256) void hist_kernel(const int* __restrict__ ei,
                                                   int* __restrict__ deg) {
  int e = blockIdx.x * blockDim.x + threadIdx.x;
  if (e >= N_EDGES) return;
  atomicAdd(deg + ei[N_EDGES + e], 1);
}

__global__ __launch_bounds__(256) void gather_kernel(
    const int* __restrict__ offs, const int* __restrict__ csr,
    const float* __restrict__ x, float* __restrict__ agg) {
  int wid = (blockIdx.x * blockDim.x + threadIdx.x) >> 6;
  if (wid >= N_NODES) return;
  int lane = threadIdx.x & 63;
  int c0 = lane * 2;
  int s = offs[wid], e = offs[wid + 1];
  float accx = 0.f, accy = 0.f;
  for (int j = s; j < e; ++j) {
    int nbr = csr[j];
    float2 v = *reinterpret_cast<const float2*>(x + (size_t)nbr * HIDDEN + c0);
    accx += v.x;
    accy += v.y;
  }
  *reinterpret_cast<float2*>(agg + (size_t)wid * HIDDEN + c0) =
      make_float2(accx, accy);
}

__global__ __launch_bounds__(256) void scatter_kernel(
    const int* __restrict__ ei, const float* __restrict__ x,
    float* __restrict__ agg) {
  long long gid = (long long)blockIdx.x * blockDim.x + threadIdx.x;
  int e = (int)(gid >> 5);
  if (e >= N_EDGES) return;
  int sub = ((int)gid & 31) * 4;
  int src = ei[e];
  int dst = ei[N_EDGES + e];
  const float4 v = *reinterpret_cast<const float4*>(x + src * HIDDEN + sub);
  float* p = agg + dst * HIDDEN + sub;
  atomicAdd(p + 0, v.x);
  atomicAdd(p + 1, v.y);
  atomicAdd(p + 2, v.z);
  atomicAdd(p + 3, v.w);
}

__global__ __launch_bounds__(512) void mlp_kernel(
    const float* __restrict__ x, float* __restrict__ io,
    const float* __restrict__ W1, const float* __restrict__ b1,
    const float* __restrict__ W2, const float* __restrict__ b2) {
  __shared__ float W1s[HIDDEN * HIDDEN];
  __shared__ float W2s[HIDDEN * HIDDEN];

  const int tid = threadIdx.x;
#pragma unroll
  for (int i = 0; i < 8; ++i) {
    int idx = (i * 512 + tid) * 4;
    *reinterpret_cast<float4*>(W1s + idx) =
        *reinterpret_cast<const float4*>(W1 + idx);
    *reinterpret_cast<float4*>(W2s + idx) =
        *reinterpret_cast<const float4*>(W2 + idx);
  }

  const int lane = tid & 63;
  const int wave = tid >> 6;
  const int c0 = 2 * lane, c1 = 2 * lane + 1;

  const float m0 = col_mask(c0);
  const float m1 = col_mask(c1);
  const float bb1x = b1[c0], bb1y = b1[c1];
  const float bb2x = b2[c0], bb2y = b2[c1];

  __syncthreads();

  const int gwave = blockIdx.x * 8 + wave;
  const int nwaves = gridDim.x * 8;

  for (int pr = gwave; pr < N_NODES / 2; pr += nwaves) {
    const int baseA = (2 * pr) * HIDDEN;
    const int baseB = baseA + HIDDEN;

    float2 xA = *reinterpret_cast<const float2*>(x + baseA + c0);
    float2 gA = *reinterpret_cast<const float2*>(io + baseA + c0);
    float2 xB = *reinterpret_cast<const float2*>(x + baseB + c0);
    float2 gB = *reinterpret_cast<const float2*>(io + baseB + c0);

    float hA0 = m0 * (xA.x + gA.x), hA1 = m1 * (xA.y + gA.y);
    float hB0 = m0 * (xB.x + gB.x), hB1 = m1 * (xB.y + gB.y);

    float aA0 = bb1x, aA1 = bb1y, aB0 = bb1x, aB1 = bb1y;
#pragma unroll
    for (int k = 0; k < HIDDEN; ++k) {
      const int sl = k >> 1;
      float hkA = (k & 1) ? rlane(hA1, sl) : rlane(hA0, sl);
      float hkB = (k & 1) ? rlane(hB1, sl) : rlane(hB0, sl);
      float2 w = *reinterpret_cast<const float2*>(W1s + k * HIDDEN + c0);
      aA0 = fmaf(hkA, w.x, aA0);
      aA1 = fmaf(hkA, w.y, aA1);
      aB0 = fmaf(hkB, w.x, aB0);
      aB1 = fmaf(hkB, w.y, aB1);
    }
    aA0 = fmaxf(aA0, 0.0f); aA1 = fmaxf(aA1, 0.0f);
    aB0 = fmaxf(aB0, 0.0f); aB1 = fmaxf(aB1, 0.0f);

    float oA0 = bb2x, oA1 = bb2y, oB0 = bb2x, oB1 = bb2y;
#pragma unroll
    for (int k = 0; k < HIDDEN; ++k) {
      const int sl = k >> 1;
      float hkA = (k & 1) ? rlane(aA1, sl) : rlane(aA0, sl);
      float hkB = (k & 1) ? rlane(aB1, sl) : rlane(aB0, sl);
      float2 w = *reinterpret_cast<const float2*>(W2s + k * HIDDEN + c0);
      oA0 = fmaf(hkA, w.x, oA0);
      oA1 = fmaf(hkA, w.y, oA1);
      oB0 = fmaf(hkB, w.x, oB0);
      oB1 = fmaf(hkB, w.y, oB1);
    }

    *reinterpret_cast<float2*>(io + baseA + c0) = make_float2(oA0, oA1);
    *reinterpret_cast<float2*>(io + baseB + c0) = make_float2(oB0, oB1);
  }
}

extern "C" void kernel_launch(void* const* d_in, const int* in_sizes, int n_in,
                              void* d_out, int out_size, void* d_ws,
                              size_t ws_size, hipStream_t stream) {
  (void)in_sizes; (void)n_in; (void)out_size;
  const float* x  = (const float*)d_in[0];
  const int*   ei = (const int*)d_in[1];
  const float* W1 = (const float*)d_in[2];
  const float* b1 = (const float*)d_in[3];
  const float* W2 = (const float*)d_in[4];
  const float* b2 = (const float*)d_in[5];
  float* out = (float*)d_out;

  // ws layout (ints): deg[N] offs[N+1] pos[N] csr[E] bsum[NB] bpre[NB]
  //                   ticket[1] | Wt1 Wt2 (bf16) | xb (bf16, N*HIDDEN)
  const size_t csr_need =
      (size_t)(N_NODES + (N_NODES + 1) + N_NODES + N_EDGES + 2 * NB + 1) * 4;
  const size_t xb_need = csr_need + 2 * (size_t)HIDDEN * HIDDEN * 2 +
                         (size_t)N_NODES * HIDDEN * 2;

  if (ws_size >= csr_need) {
    int* deg    = (int*)d_ws;
    int* offs   = deg + N_NODES;
    int* pos    = offs + N_NODES + 1;
    int* csr    = pos + N_NODES;
    int* bsum   = csr + N_EDGES;
    int* bpre   = bsum + NB;
    int* ticket = bpre + NB;

    hipMemsetAsync(deg, 0, (size_t)N_NODES * 4, stream);

    if (ws_size >= xb_need) {
      // Tier A: bf16-everything fused path with persistent fused kernel.
      unsigned short* Wt1 = (unsigned short*)(ticket + 1);
      unsigned short* Wt2 = Wt1 + HIDDEN * HIDDEN;
      unsigned short* xb  = Wt2 + HIDDEN * HIDDEN;
      const int nprep = (N_NODES * HIDDEN / 8 + 255) / 256;  // 3125 >= hist need
      prep_kernel<<<nprep, 256, 0, stream>>>(x, W1, W2, ei, xb, Wt1, Wt2, deg);
      scanA_kernel<<<NB, 256, 0, stream>>>(deg, bsum);
      scanB_kernel<<<1, 256, 0, stream>>>(bsum, bpre, offs, ticket);
      scanC_kernel<<<NB, 256, 0, stream>>>(deg, bpre, offs, pos);
      fill_kernel<<<(N_EDGES + 255) / 256, 256, 0, stream>>>(ei, pos, csr);
      fused_xb_kernel<<<2048, 256, 0, stream>>>(offs, csr, xb, Wt1, Wt2, b1,
                                                b2, ticket, out);
    } else {
      // Tier B: f32 gather + rlane MLP.
      hist_kernel<<<(N_EDGES + 255) / 256, 256, 0, stream>>>(ei, deg);
      scanA_kernel<<<NB, 256, 0, stream>>>(deg, bsum);
      scanB_kernel<<<1, 256, 0, stream>>>(bsum, bpre, offs, ticket);
      scanC_kernel<<<NB, 256, 0, stream>>>(deg, bpre, offs, pos);
      fill_kernel<<<(N_EDGES + 255) / 256, 256, 0, stream>>>(ei, pos, csr);
      gather_kernel<<<(N_NODES * 64 + 255) / 256, 256, 0, stream>>>(offs, csr,
                                                                    x, out);
      mlp_kernel<<<256, 512, 0, stream>>>(x, out, W1, b1, W2, b2);
    }
  } else {
    // Tier C: atomic scatter + rlane MLP.
    hipMemsetAsync(out, 0, (size_t)N_NODES * HIDDEN * sizeof(float), stream);
    const long long total = (long long)N_EDGES * 32;
    scatter_kernel<<<(int)((total + 255) / 256), 256, 0, stream>>>(ei, x, out);
    mlp_kernel<<<256, 512, 0, stream>>>(x, out, W1, b1, W2, b2);
  }
}

// Round 8
// 125.592 us; speedup vs baseline: 1.4470x; 1.4470x over previous
//
#include <hip/hip_runtime.h>

#define N_NODES 50000
#define HIDDEN  128
#define N_EDGES 600000
#define BR      32                        // rows per tile in fused kernel
#define NB      ((N_NODES + 255) / 256)   // 196 scan blocks
#define NTILES  ((N_NODES + BR - 1) / BR) // 1563
#define E_PAD_MAX (N_EDGES + 3 * N_NODES) // 750000 max padded csr entries

typedef __attribute__((ext_vector_type(8))) short short8v;
typedef __attribute__((ext_vector_type(4))) float f32x4;

// ---------------- threefry2x32 (JAX-exact, key = (0,42)) ----------------
__device__ __forceinline__ unsigned rotl32(unsigned v, int r) {
  return (v << r) | (v >> (32 - r));
}

__device__ __forceinline__ void threefry2x32(unsigned x0, unsigned x1,
                                             unsigned& o0, unsigned& o1) {
  const unsigned ks0 = 0u, ks1 = 42u;
  const unsigned ks2 = ks0 ^ ks1 ^ 0x1BD11BDAu;
  const unsigned ks[3] = {ks0, ks1, ks2};
  const int rot[2][4] = {{13, 15, 26, 6}, {17, 29, 16, 24}};
  x0 += ks0; x1 += ks1;
#pragma unroll
  for (int i = 0; i < 5; ++i) {
#pragma unroll
    for (int j = 0; j < 4; ++j) {
      x0 += x1;
      x1 = rotl32(x1, rot[i & 1][j]);
      x1 ^= x0;
    }
    x0 += ks[(i + 1) % 3];
    x1 += ks[(i + 2) % 3] + (unsigned)(i + 1);
  }
  o0 = x0; o1 = x1;
}

// JAX threefry_partitionable random_bits: bits[c] = o0^o1 of
// threefry(key=(0,42), counter=(0,c)); uniform = ((bits>>9)|0x3f800000)-1.
__device__ __forceinline__ float col_mask(int c) {
  unsigned o0, o1;
  threefry2x32(0u, (unsigned)c, o0, o1);
  unsigned bits = o0 ^ o1;
  float u = __uint_as_float((bits >> 9) | 0x3f800000u) - 1.0f;
  return (u < 0.75f) ? 1.0f : 0.0f;
}

__device__ __forceinline__ unsigned short f2bf(float f) {
  unsigned u = __float_as_uint(f);
  u += 0x7fffu + ((u >> 16) & 1u);  // round-to-nearest-even
  return (unsigned short)(u >> 16);
}

__device__ __forceinline__ float bflo(unsigned u) {
  return __uint_as_float(u << 16);
}
__device__ __forceinline__ float bfhi(unsigned u) {
  return __uint_as_float(u & 0xffff0000u);
}

__device__ __forceinline__ float rlane(float v, int l) {
  return __int_as_float(__builtin_amdgcn_readlane(__float_as_int(v), l));
}

// ---------------- prep: hist(dst) + xb = bf16(mask .* x) + Wt = bf16(W^T) --
// 3125 blocks x 256 threads; thread handles 8 xb elements; gid<N_EDGES also
// histograms; gid<4096 transposes 4 elements of each W; gid<16 zeros the
// dummy row xb[N_NODES] (target of csr padding entries).
__global__ __launch_bounds__(256) void prep_kernel(
    const float* __restrict__ x, const float* __restrict__ W1,
    const float* __restrict__ W2, const int* __restrict__ ei,
    unsigned short* __restrict__ xb, unsigned short* __restrict__ Wt1,
    unsigned short* __restrict__ Wt2, int* __restrict__ deg) {
  __shared__ float msk[HIDDEN];
  if (threadIdx.x < HIDDEN) msk[threadIdx.x] = col_mask(threadIdx.x);
  __syncthreads();

  const int gid = blockIdx.x * 256 + threadIdx.x;
  const int e0 = gid * 8;  // 8 contiguous elements
  if (e0 < N_NODES * HIDDEN) {
    const int c0 = e0 & (HIDDEN - 1);
    const float4 v0 = *reinterpret_cast<const float4*>(x + e0);
    const float4 v1 = *reinterpret_cast<const float4*>(x + e0 + 4);
    unsigned short h[8];
    h[0] = f2bf(v0.x * msk[c0 + 0]);
    h[1] = f2bf(v0.y * msk[c0 + 1]);
    h[2] = f2bf(v0.z * msk[c0 + 2]);
    h[3] = f2bf(v0.w * msk[c0 + 3]);
    h[4] = f2bf(v1.x * msk[c0 + 4]);
    h[5] = f2bf(v1.y * msk[c0 + 5]);
    h[6] = f2bf(v1.z * msk[c0 + 6]);
    h[7] = f2bf(v1.w * msk[c0 + 7]);
    *reinterpret_cast<uint4*>(xb + e0) = *reinterpret_cast<uint4*>(h);
  }
  if (gid < N_EDGES) atomicAdd(deg + ei[N_EDGES + gid], 1);
  if (gid < HIDDEN * HIDDEN / 4) {
#pragma unroll
    for (int i = 0; i < 4; ++i) {
      int t = gid * 4 + i;            // Wt index
      int col = t >> 7, k = t & 127;  // Wt[col][k] = W[k][col]
      Wt1[t] = f2bf(W1[k * HIDDEN + col]);
      Wt2[t] = f2bf(W2[k * HIDDEN + col]);
    }
  }
  if (gid < 16) {
    uint4 z; z.x = 0; z.y = 0; z.z = 0; z.w = 0;
    *reinterpret_cast<uint4*>(xb + (size_t)N_NODES * HIDDEN + gid * 8) = z;
  }
}

// ---------------- two-level scan over PADDED degrees ----------------
__global__ __launch_bounds__(256) void scanA_kernel(const int* __restrict__ deg,
                                                    int* __restrict__ bsum) {
  int idx = blockIdx.x * 256 + threadIdx.x;
  int v = (idx < N_NODES) ? ((deg[idx] + 3) & ~3) : 0;
#pragma unroll
  for (int off = 32; off; off >>= 1) v += __shfl_down(v, off, 64);
  __shared__ int ws4[4];
  if ((threadIdx.x & 63) == 0) ws4[threadIdx.x >> 6] = v;
  __syncthreads();
  if (threadIdx.x == 0) bsum[blockIdx.x] = ws4[0] + ws4[1] + ws4[2] + ws4[3];
}

__global__ __launch_bounds__(256) void scanB_kernel(const int* __restrict__ bsum,
                                                    int* __restrict__ bpre,
                                                    int* __restrict__ offs) {
  __shared__ int s[256];
  const int t = threadIdx.x;
  int v = (t < NB) ? bsum[t] : 0;
  s[t] = v;
  __syncthreads();
  int acc = v;
  for (int off = 1; off < 256; off <<= 1) {
    int add = (t >= off) ? s[t - off] : 0;
    __syncthreads();
    acc += add;
    s[t] = acc;
    __syncthreads();
  }
  if (t < NB) bpre[t] = acc - v;              // exclusive prefix
  if (t == 0) offs[N_NODES] = s[255];         // total padded edge count
}

// Stage C: local scan of padded degrees + write pad slots (dummy node).
__global__ __launch_bounds__(256) void scanC_kernel(
    const int* __restrict__ deg, const int* __restrict__ bpre,
    int* __restrict__ offs, int* __restrict__ pos,
    unsigned short* __restrict__ csr) {
  __shared__ int s[256];
  const int t = threadIdx.x;
  const int idx = blockIdx.x * 256 + t;
  int d = (idx < N_NODES) ? deg[idx] : 0;
  int v = (d + 3) & ~3;
  s[t] = v;
  __syncthreads();
  int acc = v;
  for (int off = 1; off < 256; off <<= 1) {
    int add = (t >= off) ? s[t - off] : 0;
    __syncthreads();
    acc += add;
    s[t] = acc;
    __syncthreads();
  }
  if (idx < N_NODES) {
    int o = bpre[blockIdx.x] + acc - v;
    offs[idx] = o;
    pos[idx] = o;
    for (int w = o + d; w < o + v; ++w)
      csr[w] = (unsigned short)N_NODES;  // pad -> zero row
  }
}

__global__ __launch_bounds__(256) void fill_kernel(const int* __restrict__ ei,
                                                   int* __restrict__ pos,
                                                   unsigned short* __restrict__ csr) {
  int e = blockIdx.x * blockDim.x + threadIdx.x;
  if (e >= N_EDGES) return;
  int src = ei[e];
  int dst = ei[N_EDGES + e];
  int p = atomicAdd(pos + dst, 1);
  csr[p] = (unsigned short)src;
}

// ---------------- fused gather(bf16) + MLP (bf16 MFMA) ----------------
// Block: 32 node-rows, 256 threads (4 waves). Gather: half-wave per row —
// lanes 0-31 row A, lanes 32-63 row B; each lane owns 4 cols (uint2/8B).
// Every load instruction fetches TWO rows (512B) -> 8 rows in flight per
// wave with a 4-deep ladder. CSR padded to deg%4==0 (pad -> zero row), so
// no tail handling. Then wave w computes output cols [32w, 32w+32).
__global__ __launch_bounds__(256) void fused_xb_kernel(
    const int* __restrict__ offs, const unsigned short* __restrict__ csr,
    const unsigned short* __restrict__ xb,
    const unsigned short* __restrict__ Wt1,
    const unsigned short* __restrict__ Wt2, const float* __restrict__ b1,
    const float* __restrict__ b2, float* __restrict__ out) {
  __shared__ unsigned short H1[BR * HIDDEN];  // 8 KB, swizzled
  __shared__ unsigned short H2[BR * HIDDEN];  // 8 KB, swizzled

  const int tid = threadIdx.x;
  const int lane = tid & 63;
  const int wave = tid >> 6;
  const int half = lane >> 5;  // 0: row A, 1: row B
  const int hl = lane & 31;    // lane within half; cols hl*4 .. hl*4+3
  const int base = blockIdx.x * BR;

  // ---- phase 1: gather (mask baked into xb) -> H1, two rows per iter ----
#pragma unroll 1
  for (int i = 0; i < 4; ++i) {
    const int row = wave * 8 + 2 * i + half;
    const int node = base + row;
    const bool valid = node < N_NODES;
    const int na = valid ? node : 0;
    int s = offs[na];
    int e = offs[na + 1];
    s = valid ? s : 0;
    e = valid ? e : 0;
    const int on = valid ? node : N_NODES;  // invalid -> zero row
    const uint2 ov =
        *reinterpret_cast<const uint2*>(xb + (size_t)on * HIDDEN + hl * 4);
    float a0 = bflo(ov.x), a1 = bfhi(ov.x);
    float a2 = bflo(ov.y), a3 = bfhi(ov.y);

    const int it = (e - s) >> 2;  // padded: exact multiple of 4
    const int m = max(__builtin_amdgcn_readlane(it, 0),
                      __builtin_amdgcn_readlane(it, 32));
    int j = s;
    for (int t = 0; t < m; ++t) {
      const bool v4 = j < e;
      const int jc = v4 ? j : 0;
      const int i0 = v4 ? (int)csr[jc + 0] : N_NODES;
      const int i1 = v4 ? (int)csr[jc + 1] : N_NODES;
      const int i2 = v4 ? (int)csr[jc + 2] : N_NODES;
      const int i3 = v4 ? (int)csr[jc + 3] : N_NODES;
      const uint2 u0 =
          *reinterpret_cast<const uint2*>(xb + (size_t)i0 * HIDDEN + hl * 4);
      const uint2 u1 =
          *reinterpret_cast<const uint2*>(xb + (size_t)i1 * HIDDEN + hl * 4);
      const uint2 u2 =
          *reinterpret_cast<const uint2*>(xb + (size_t)i2 * HIDDEN + hl * 4);
      const uint2 u3 =
          *reinterpret_cast<const uint2*>(xb + (size_t)i3 * HIDDEN + hl * 4);
      a0 += bflo(u0.x) + bflo(u1.x) + bflo(u2.x) + bflo(u3.x);
      a1 += bfhi(u0.x) + bfhi(u1.x) + bfhi(u2.x) + bfhi(u3.x);
      a2 += bflo(u0.y) + bflo(u1.y) + bflo(u2.y) + bflo(u3.y);
      a3 += bfhi(u0.y) + bfhi(u1.y) + bfhi(u2.y) + bfhi(u3.y);
      j += 4;
    }
    unsigned p0 = (unsigned)f2bf(a0) | ((unsigned)f2bf(a1) << 16);
    unsigned p1 = (unsigned)f2bf(a2) | ((unsigned)f2bf(a3) << 16);
    const int byte = (row * 256 + hl * 8) ^ ((row & 7) << 4);
    uint2 pw; pw.x = p0; pw.y = p1;
    *reinterpret_cast<uint2*>(reinterpret_cast<char*>(H1) + byte) = pw;
  }
  __syncthreads();

  // ---- phase 2: GEMM1 (H1 @ Wt1 + b1, relu) -> H2 ----
  const int colbase = wave * 32;  // 2 col-tiles per wave
  float bias1[2], bias2[2];
#pragma unroll
  for (int c = 0; c < 2; ++c) {
    bias1[c] = b1[colbase + c * 16 + (lane & 15)];
    bias2[c] = b2[colbase + c * 16 + (lane & 15)];
  }

  f32x4 acc[2][2] = {};
#pragma unroll
  for (int kt = 0; kt < 4; ++kt) {
    short8v a[2], b[2];
#pragma unroll
    for (int r = 0; r < 2; ++r) {
      int row = r * 16 + (lane & 15);
      int byte = (row * 256 + kt * 64 + (lane >> 4) * 16) ^ ((row & 7) << 4);
      a[r] = *reinterpret_cast<const short8v*>(
          reinterpret_cast<const char*>(H1) + byte);
    }
#pragma unroll
    for (int c = 0; c < 2; ++c) {
      int col = colbase + c * 16 + (lane & 15);
      b[c] = *reinterpret_cast<const short8v*>(
          reinterpret_cast<const char*>(Wt1) + col * 256 + kt * 64 +
          (lane >> 4) * 16);
    }
#pragma unroll
    for (int r = 0; r < 2; ++r)
#pragma unroll
      for (int c = 0; c < 2; ++c)
        acc[r][c] = __builtin_amdgcn_mfma_f32_16x16x32_bf16(a[r], b[c],
                                                            acc[r][c], 0, 0, 0);
  }
#pragma unroll
  for (int r = 0; r < 2; ++r)
#pragma unroll
    for (int c = 0; c < 2; ++c)
#pragma unroll
      for (int q = 0; q < 4; ++q) {
        int row = r * 16 + (lane >> 4) * 4 + q;
        int col = colbase + c * 16 + (lane & 15);
        float v = fmaxf(acc[r][c][q] + bias1[c], 0.f);
        int byte = (row * 256 + col * 2) ^ ((row & 7) << 4);
        *reinterpret_cast<unsigned short*>(reinterpret_cast<char*>(H2) + byte) =
            f2bf(v);
      }
  __syncthreads();

  // ---- phase 3: GEMM2 (H2 @ Wt2 + b2) -> out ----
  f32x4 acc2[2][2] = {};
#pragma unroll
  for (int kt = 0; kt < 4; ++kt) {
    short8v a[2], b[2];
#pragma unroll
    for (int r = 0; r < 2; ++r) {
      int row = r * 16 + (lane & 15);
      int byte = (row * 256 + kt * 64 + (lane >> 4) * 16) ^ ((row & 7) << 4);
      a[r] = *reinterpret_cast<const short8v*>(
          reinterpret_cast<const char*>(H2) + byte);
    }
#pragma unroll
    for (int c = 0; c < 2; ++c) {
      int col = colbase + c * 16 + (lane & 15);
      b[c] = *reinterpret_cast<const short8v*>(
          reinterpret_cast<const char*>(Wt2) + col * 256 + kt * 64 +
          (lane >> 4) * 16);
    }
#pragma unroll
    for (int r = 0; r < 2; ++r)
#pragma unroll
      for (int c = 0; c < 2; ++c)
        acc2[r][c] = __builtin_amdgcn_mfma_f32_16x16x32_bf16(
            a[r], b[c], acc2[r][c], 0, 0, 0);
  }
#pragma unroll
  for (int r = 0; r < 2; ++r)
#pragma unroll
    for (int c = 0; c < 2; ++c)
#pragma unroll
      for (int q = 0; q < 4; ++q) {
        int row = base + r * 16 + (lane >> 4) * 4 + q;
        if (row < N_NODES) {
          int col = colbase + c * 16 + (lane & 15);
          out[(size_t)row * HIDDEN + col] = acc2[r][c][q] + bias2[c];
        }
      }
}

// ---------------- Tier-C fallback (round-2 proven) ----------------
__global__ __launch_bounds__(256) void scatter_kernel(
    const int* __restrict__ ei, const float* __restrict__ x,
    float* __restrict__ agg) {
  long long gid = (long long)blockIdx.x * blockDim.x + threadIdx.x;
  int e = (int)(gid >> 5);
  if (e >= N_EDGES) return;
  int sub = ((int)gid & 31) * 4;
  int src = ei[e];
  int dst = ei[N_EDGES + e];
  const float4 v = *reinterpret_cast<const float4*>(x + src * HIDDEN + sub);
  float* p = agg + dst * HIDDEN + sub;
  atomicAdd(p + 0, v.x);
  atomicAdd(p + 1, v.y);
  atomicAdd(p + 2, v.z);
  atomicAdd(p + 3, v.w);
}

__global__ __launch_bounds__(512) void mlp_kernel(
    const float* __restrict__ x, float* __restrict__ io,
    const float* __restrict__ W1, const float* __restrict__ b1,
    const float* __restrict__ W2, const float* __restrict__ b2) {
  __shared__ float W1s[HIDDEN * HIDDEN];
  __shared__ float W2s[HIDDEN * HIDDEN];

  const int tid = threadIdx.x;
#pragma unroll
  for (int i = 0; i < 8; ++i) {
    int idx = (i * 512 + tid) * 4;
    *reinterpret_cast<float4*>(W1s + idx) =
        *reinterpret_cast<const float4*>(W1 + idx);
    *reinterpret_cast<float4*>(W2s + idx) =
        *reinterpret_cast<const float4*>(W2 + idx);
  }

  const int lane = tid & 63;
  const int wave = tid >> 6;
  const int c0 = 2 * lane, c1 = 2 * lane + 1;

  const float m0 = col_mask(c0);
  const float m1 = col_mask(c1);
  const float bb1x = b1[c0], bb1y = b1[c1];
  const float bb2x = b2[c0], bb2y = b2[c1];

  __syncthreads();

  const int gwave = blockIdx.x * 8 + wave;
  const int nwaves = gridDim.x * 8;

  for (int pr = gwave; pr < N_NODES / 2; pr += nwaves) {
    const int baseA = (2 * pr) * HIDDEN;
    const int baseB = baseA + HIDDEN;

    float2 xA = *reinterpret_cast<const float2*>(x + baseA + c0);
    float2 gA = *reinterpret_cast<const float2*>(io + baseA + c0);
    float2 xB = *reinterpret_cast<const float2*>(x + baseB + c0);
    float2 gB = *reinterpret_cast<const float2*>(io + baseB + c0);

    float hA0 = m0 * (xA.x + gA.x), hA1 = m1 * (xA.y + gA.y);
    float hB0 = m0 * (xB.x + gB.x), hB1 = m1 * (xB.y + gB.y);

    float aA0 = bb1x, aA1 = bb1y, aB0 = bb1x, aB1 = bb1y;
#pragma unroll
    for (int k = 0; k < HIDDEN; ++k) {
      const int sl = k >> 1;
      float hkA = (k & 1) ? rlane(hA1, sl) : rlane(hA0, sl);
      float hkB = (k & 1) ? rlane(hB1, sl) : rlane(hB0, sl);
      float2 w = *reinterpret_cast<const float2*>(W1s + k * HIDDEN + c0);
      aA0 = fmaf(hkA, w.x, aA0);
      aA1 = fmaf(hkA, w.y, aA1);
      aB0 = fmaf(hkB, w.x, aB0);
      aB1 = fmaf(hkB, w.y, aB1);
    }
    aA0 = fmaxf(aA0, 0.0f); aA1 = fmaxf(aA1, 0.0f);
    aB0 = fmaxf(aB0, 0.0f); aB1 = fmaxf(aB1, 0.0f);

    float oA0 = bb2x, oA1 = bb2y, oB0 = bb2x, oB1 = bb2y;
#pragma unroll
    for (int k = 0; k < HIDDEN; ++k) {
      const int sl = k >> 1;
      float hkA = (k & 1) ? rlane(aA1, sl) : rlane(aA0, sl);
      float hkB = (k & 1) ? rlane(aB1, sl) : rlane(aB0, sl);
      float2 w = *reinterpret_cast<const float2*>(W2s + k * HIDDEN + c0);
      oA0 = fmaf(hkA, w.x, oA0);
      oA1 = fmaf(hkA, w.y, oA1);
      oB0 = fmaf(hkB, w.x, oB0);
      oB1 = fmaf(hkB, w.y, oB1);
    }

    *reinterpret_cast<float2*>(io + baseA + c0) = make_float2(oA0, oA1);
    *reinterpret_cast<float2*>(io + baseB + c0) = make_float2(oB0, oB1);
  }
}

extern "C" void kernel_launch(void* const* d_in, const int* in_sizes, int n_in,
                              void* d_out, int out_size, void* d_ws,
                              size_t ws_size, hipStream_t stream) {
  (void)in_sizes; (void)n_in; (void)out_size;
  const float* x  = (const float*)d_in[0];
  const int*   ei = (const int*)d_in[1];
  const float* W1 = (const float*)d_in[2];
  const float* b1 = (const float*)d_in[3];
  const float* W2 = (const float*)d_in[4];
  const float* b2 = (const float*)d_in[5];
  float* out = (float*)d_out;

  // ws layout: [ints: deg N | offs N+1 | pos N | bsum NB | bpre NB] pad16
  //            [u16: csr E_PAD_MAX] [u16: Wt1 16384 | Wt2 16384]
  //            [u16: xb (N_NODES+1)*HIDDEN]
  const size_t int_bytes = (size_t)(N_NODES + (N_NODES + 1) + N_NODES + 2 * NB) * 4;
  const size_t int_pad   = (int_bytes + 15) & ~(size_t)15;
  const size_t csr_bytes = (size_t)E_PAD_MAX * 2;
  const size_t wt_bytes  = 2 * (size_t)HIDDEN * HIDDEN * 2;
  const size_t xb_bytes  = (size_t)(N_NODES + 1) * HIDDEN * 2;
  const size_t need = int_pad + csr_bytes + wt_bytes + xb_bytes;

  if (ws_size >= need) {
    char* wsb = (char*)d_ws;
    int* deg  = (int*)wsb;
    int* offs = deg + N_NODES;
    int* pos  = offs + N_NODES + 1;
    int* bsum = pos + N_NODES;
    int* bpre = bsum + NB;
    unsigned short* csr = (unsigned short*)(wsb + int_pad);
    unsigned short* Wt1 = (unsigned short*)(wsb + int_pad + csr_bytes);
    unsigned short* Wt2 = Wt1 + HIDDEN * HIDDEN;
    unsigned short* xb  = Wt2 + HIDDEN * HIDDEN;

    hipMemsetAsync(deg, 0, (size_t)N_NODES * 4, stream);
    const int nprep = (N_NODES * HIDDEN / 8 + 255) / 256;  // 3125
    prep_kernel<<<nprep, 256, 0, stream>>>(x, W1, W2, ei, xb, Wt1, Wt2, deg);
    scanA_kernel<<<NB, 256, 0, stream>>>(deg, bsum);
    scanB_kernel<<<1, 256, 0, stream>>>(bsum, bpre, offs);
    scanC_kernel<<<NB, 256, 0, stream>>>(deg, bpre, offs, pos, csr);
    fill_kernel<<<(N_EDGES + 255) / 256, 256, 0, stream>>>(ei, pos, csr);
    fused_xb_kernel<<<NTILES, 256, 0, stream>>>(offs, csr, xb, Wt1, Wt2, b1,
                                                b2, out);
  } else {
    // Tier C: atomic scatter + rlane MLP (proven, slow).
    hipMemsetAsync(out, 0, (size_t)N_NODES * HIDDEN * sizeof(float), stream);
    const long long total = (long long)N_EDGES * 32;
    scatter_kernel<<<(int)((total + 255) / 256), 256, 0, stream>>>(ei, x, out);
    mlp_kernel<<<256, 512, 0, stream>>>(x, out, W1, b1, W2, b2);
  }
}

// Round 9
// 117.758 us; speedup vs baseline: 1.5433x; 1.0665x over previous
//
#include <hip/hip_runtime.h>

#define N_NODES 50000
#define HIDDEN  128
#define N_EDGES 600000
#define BR      32                        // rows per tile in fused kernel
#define NB      ((N_NODES + 255) / 256)   // 196 scan blocks
#define NTILES  ((N_NODES + BR - 1) / BR) // 1563
#define E_PAD_MAX (N_EDGES + 3 * N_NODES) // 750000 max padded csr entries
#define SCSR_CAP 4096                     // staged csr entries per tile (8KB)

typedef __attribute__((ext_vector_type(8))) short short8v;
typedef __attribute__((ext_vector_type(4))) float f32x4;

// ---------------- threefry2x32 (JAX-exact, key = (0,42)) ----------------
__device__ __forceinline__ unsigned rotl32(unsigned v, int r) {
  return (v << r) | (v >> (32 - r));
}

__device__ __forceinline__ void threefry2x32(unsigned x0, unsigned x1,
                                             unsigned& o0, unsigned& o1) {
  const unsigned ks0 = 0u, ks1 = 42u;
  const unsigned ks2 = ks0 ^ ks1 ^ 0x1BD11BDAu;
  const unsigned ks[3] = {ks0, ks1, ks2};
  const int rot[2][4] = {{13, 15, 26, 6}, {17, 29, 16, 24}};
  x0 += ks0; x1 += ks1;
#pragma unroll
  for (int i = 0; i < 5; ++i) {
#pragma unroll
    for (int j = 0; j < 4; ++j) {
      x0 += x1;
      x1 = rotl32(x1, rot[i & 1][j]);
      x1 ^= x0;
    }
    x0 += ks[(i + 1) % 3];
    x1 += ks[(i + 2) % 3] + (unsigned)(i + 1);
  }
  o0 = x0; o1 = x1;
}

// JAX threefry_partitionable random_bits: bits[c] = o0^o1 of
// threefry(key=(0,42), counter=(0,c)); uniform = ((bits>>9)|0x3f800000)-1.
__device__ __forceinline__ float col_mask(int c) {
  unsigned o0, o1;
  threefry2x32(0u, (unsigned)c, o0, o1);
  unsigned bits = o0 ^ o1;
  float u = __uint_as_float((bits >> 9) | 0x3f800000u) - 1.0f;
  return (u < 0.75f) ? 1.0f : 0.0f;
}

__device__ __forceinline__ unsigned short f2bf(float f) {
  unsigned u = __float_as_uint(f);
  u += 0x7fffu + ((u >> 16) & 1u);  // round-to-nearest-even
  return (unsigned short)(u >> 16);
}

__device__ __forceinline__ float bflo(unsigned u) {
  return __uint_as_float(u << 16);
}
__device__ __forceinline__ float bfhi(unsigned u) {
  return __uint_as_float(u & 0xffff0000u);
}

__device__ __forceinline__ float rlane(float v, int l) {
  return __int_as_float(__builtin_amdgcn_readlane(__float_as_int(v), l));
}

// ---------------- prep: hist(dst) + xb = bf16(mask .* x) + Wt = bf16(W^T) --
__global__ __launch_bounds__(256) void prep_kernel(
    const float* __restrict__ x, const float* __restrict__ W1,
    const float* __restrict__ W2, const int* __restrict__ ei,
    unsigned short* __restrict__ xb, unsigned short* __restrict__ Wt1,
    unsigned short* __restrict__ Wt2, int* __restrict__ deg) {
  __shared__ float msk[HIDDEN];
  if (threadIdx.x < HIDDEN) msk[threadIdx.x] = col_mask(threadIdx.x);
  __syncthreads();

  const int gid = blockIdx.x * 256 + threadIdx.x;
  const int e0 = gid * 8;  // 8 contiguous elements
  if (e0 < N_NODES * HIDDEN) {
    const int c0 = e0 & (HIDDEN - 1);
    const float4 v0 = *reinterpret_cast<const float4*>(x + e0);
    const float4 v1 = *reinterpret_cast<const float4*>(x + e0 + 4);
    unsigned short h[8];
    h[0] = f2bf(v0.x * msk[c0 + 0]);
    h[1] = f2bf(v0.y * msk[c0 + 1]);
    h[2] = f2bf(v0.z * msk[c0 + 2]);
    h[3] = f2bf(v0.w * msk[c0 + 3]);
    h[4] = f2bf(v1.x * msk[c0 + 4]);
    h[5] = f2bf(v1.y * msk[c0 + 5]);
    h[6] = f2bf(v1.z * msk[c0 + 6]);
    h[7] = f2bf(v1.w * msk[c0 + 7]);
    *reinterpret_cast<uint4*>(xb + e0) = *reinterpret_cast<uint4*>(h);
  }
  if (gid < N_EDGES) atomicAdd(deg + ei[N_EDGES + gid], 1);
  if (gid < HIDDEN * HIDDEN / 4) {
#pragma unroll
    for (int i = 0; i < 4; ++i) {
      int t = gid * 4 + i;            // Wt index
      int col = t >> 7, k = t & 127;  // Wt[col][k] = W[k][col]
      Wt1[t] = f2bf(W1[k * HIDDEN + col]);
      Wt2[t] = f2bf(W2[k * HIDDEN + col]);
    }
  }
  if (gid < 16) {
    uint4 z; z.x = 0; z.y = 0; z.z = 0; z.w = 0;
    *reinterpret_cast<uint4*>(xb + (size_t)N_NODES * HIDDEN + gid * 8) = z;
  }
}

// ---------------- two-level scan over PADDED degrees ----------------
__global__ __launch_bounds__(256) void scanA_kernel(const int* __restrict__ deg,
                                                    int* __restrict__ bsum) {
  int idx = blockIdx.x * 256 + threadIdx.x;
  int v = (idx < N_NODES) ? ((deg[idx] + 3) & ~3) : 0;
#pragma unroll
  for (int off = 32; off; off >>= 1) v += __shfl_down(v, off, 64);
  __shared__ int ws4[4];
  if ((threadIdx.x & 63) == 0) ws4[threadIdx.x >> 6] = v;
  __syncthreads();
  if (threadIdx.x == 0) bsum[blockIdx.x] = ws4[0] + ws4[1] + ws4[2] + ws4[3];
}

__global__ __launch_bounds__(256) void scanB_kernel(const int* __restrict__ bsum,
                                                    int* __restrict__ bpre,
                                                    int* __restrict__ offs) {
  __shared__ int s[256];
  const int t = threadIdx.x;
  int v = (t < NB) ? bsum[t] : 0;
  s[t] = v;
  __syncthreads();
  int acc = v;
  for (int off = 1; off < 256; off <<= 1) {
    int add = (t >= off) ? s[t - off] : 0;
    __syncthreads();
    acc += add;
    s[t] = acc;
    __syncthreads();
  }
  if (t < NB) bpre[t] = acc - v;              // exclusive prefix
  if (t == 0) offs[N_NODES] = s[255];         // total padded edge count
}

// Stage C: local scan of padded degrees + write pad slots (dummy node).
__global__ __launch_bounds__(256) void scanC_kernel(
    const int* __restrict__ deg, const int* __restrict__ bpre,
    int* __restrict__ offs, int* __restrict__ pos,
    unsigned short* __restrict__ csr) {
  __shared__ int s[256];
  const int t = threadIdx.x;
  const int idx = blockIdx.x * 256 + t;
  int d = (idx < N_NODES) ? deg[idx] : 0;
  int v = (d + 3) & ~3;
  s[t] = v;
  __syncthreads();
  int acc = v;
  for (int off = 1; off < 256; off <<= 1) {
    int add = (t >= off) ? s[t - off] : 0;
    __syncthreads();
    acc += add;
    s[t] = acc;
    __syncthreads();
  }
  if (idx < N_NODES) {
    int o = bpre[blockIdx.x] + acc - v;
    offs[idx] = o;
    pos[idx] = o;
    for (int w = o + d; w < o + v; ++w)
      csr[w] = (unsigned short)N_NODES;  // pad -> zero row
  }
}

__global__ __launch_bounds__(256) void fill_kernel(const int* __restrict__ ei,
                                                   int* __restrict__ pos,
                                                   unsigned short* __restrict__ csr) {
  int e = blockIdx.x * blockDim.x + threadIdx.x;
  if (e >= N_EDGES) return;
  int src = ei[e];
  int dst = ei[N_EDGES + e];
  int p = atomicAdd(pos + dst, 1);
  csr[p] = (unsigned short)src;
}

// ---------------- gather helper: quarter-wave rows ----------------
// 16 lanes per row (uint4/16B each -> 256B row). Wave covers 4 rows per
// instruction; 2 serial outer iterations for its 8 rows. Indices from LDS
// (staged) or global csr, with one-iteration prefetch.
template <bool LDSIDX>
__device__ __forceinline__ void gather2(
    int base, int wave, int q, int ql, int cs,
    const unsigned short* __restrict__ csr, const unsigned short* scsr,
    const int* loffs, const unsigned short* __restrict__ xb,
    unsigned short* H1) {
#pragma unroll
  for (int i = 0; i < 2; ++i) {
    const int row = wave * 8 + i * 4 + q;
    const int node = base + row;
    const bool valid = node < N_NODES;
    const int s = valid ? loffs[row] : 0;
    const int e = valid ? loffs[row + 1] : 0;
    const int on = valid ? node : N_NODES;  // invalid -> zero row
    const uint4 ov =
        *reinterpret_cast<const uint4*>(xb + (size_t)on * HIDDEN + ql * 8);
    float a0 = bflo(ov.x), a1 = bfhi(ov.x);
    float a2 = bflo(ov.y), a3 = bfhi(ov.y);
    float a4 = bflo(ov.z), a5 = bfhi(ov.z);
    float a6 = bflo(ov.w), a7 = bfhi(ov.w);

    uint2 pk; pk.x = 0; pk.y = 0;
    if (s < e) {
      pk = LDSIDX ? *reinterpret_cast<const uint2*>(scsr + (s - cs))
                  : *reinterpret_cast<const uint2*>(csr + s);
    }
    for (int j = s; j < e; j += 4) {
      const unsigned px = pk.x, py = pk.y;
      if (j + 4 < e) {
        pk = LDSIDX ? *reinterpret_cast<const uint2*>(scsr + (j + 4 - cs))
                    : *reinterpret_cast<const uint2*>(csr + j + 4);
      }
      const int i0 = (int)(px & 0xffffu), i1 = (int)(px >> 16);
      const int i2 = (int)(py & 0xffffu), i3 = (int)(py >> 16);
      const uint4 u0 =
          *reinterpret_cast<const uint4*>(xb + (size_t)i0 * HIDDEN + ql * 8);
      const uint4 u1 =
          *reinterpret_cast<const uint4*>(xb + (size_t)i1 * HIDDEN + ql * 8);
      const uint4 u2 =
          *reinterpret_cast<const uint4*>(xb + (size_t)i2 * HIDDEN + ql * 8);
      const uint4 u3 =
          *reinterpret_cast<const uint4*>(xb + (size_t)i3 * HIDDEN + ql * 8);
      a0 += bflo(u0.x) + bflo(u1.x) + bflo(u2.x) + bflo(u3.x);
      a1 += bfhi(u0.x) + bfhi(u1.x) + bfhi(u2.x) + bfhi(u3.x);
      a2 += bflo(u0.y) + bflo(u1.y) + bflo(u2.y) + bflo(u3.y);
      a3 += bfhi(u0.y) + bfhi(u1.y) + bfhi(u2.y) + bfhi(u3.y);
      a4 += bflo(u0.z) + bflo(u1.z) + bflo(u2.z) + bflo(u3.z);
      a5 += bfhi(u0.z) + bfhi(u1.z) + bfhi(u2.z) + bfhi(u3.z);
      a6 += bflo(u0.w) + bflo(u1.w) + bflo(u2.w) + bflo(u3.w);
      a7 += bfhi(u0.w) + bfhi(u1.w) + bfhi(u2.w) + bfhi(u3.w);
    }
    uint4 pw;
    pw.x = (unsigned)f2bf(a0) | ((unsigned)f2bf(a1) << 16);
    pw.y = (unsigned)f2bf(a2) | ((unsigned)f2bf(a3) << 16);
    pw.z = (unsigned)f2bf(a4) | ((unsigned)f2bf(a5) << 16);
    pw.w = (unsigned)f2bf(a6) | ((unsigned)f2bf(a7) << 16);
    const int byte = (row * 256 + ql * 16) ^ ((row & 7) << 4);
    *reinterpret_cast<uint4*>(reinterpret_cast<char*>(H1) + byte) = pw;
  }
}

// ---------------- fused gather(bf16) + MLP (bf16 MFMA) ----------------
__global__ __launch_bounds__(256) void fused_xb_kernel(
    const int* __restrict__ offs, const unsigned short* __restrict__ csr,
    const unsigned short* __restrict__ xb,
    const unsigned short* __restrict__ Wt1,
    const unsigned short* __restrict__ Wt2, const float* __restrict__ b1,
    const float* __restrict__ b2, float* __restrict__ out) {
  __shared__ unsigned short H1[BR * HIDDEN];   // 8 KB, swizzled
  __shared__ unsigned short H2[BR * HIDDEN];   // 8 KB, swizzled
  __shared__ unsigned short scsr[SCSR_CAP];    // 8 KB staged csr slice
  __shared__ int loffs[BR + 1];

  const int tid = threadIdx.x;
  const int lane = tid & 63;
  const int wave = tid >> 6;
  const int base = blockIdx.x * BR;

  if (tid < BR + 1) {
    int idx = base + tid;
    loffs[tid] = offs[idx > N_NODES ? N_NODES : idx];
  }
  __syncthreads();
  const int cs = loffs[0];
  const int count = loffs[BR] - cs;
  const bool stage = (count <= SCSR_CAP);
  if (stage) {
    const unsigned* src = reinterpret_cast<const unsigned*>(csr + cs);
    unsigned* dst = reinterpret_cast<unsigned*>(scsr);
    for (int k = tid; k < (count >> 1); k += 256) dst[k] = src[k];
  }
  __syncthreads();

  const int q = lane >> 4;   // quarter index: which row of the 4
  const int ql = lane & 15;  // lane in quarter: cols ql*8 .. ql*8+7

  if (stage)
    gather2<true>(base, wave, q, ql, cs, csr, scsr, loffs, xb, H1);
  else
    gather2<false>(base, wave, q, ql, cs, csr, scsr, loffs, xb, H1);
  __syncthreads();

  // ---- phase 2: GEMM1 (H1 @ Wt1 + b1, relu) -> H2 ----
  const int colbase = wave * 32;  // 2 col-tiles per wave
  float bias1[2], bias2[2];
#pragma unroll
  for (int c = 0; c < 2; ++c) {
    bias1[c] = b1[colbase + c * 16 + (lane & 15)];
    bias2[c] = b2[colbase + c * 16 + (lane & 15)];
  }

  f32x4 acc[2][2] = {};
#pragma unroll
  for (int kt = 0; kt < 4; ++kt) {
    short8v a[2], b[2];
#pragma unroll
    for (int r = 0; r < 2; ++r) {
      int row = r * 16 + (lane & 15);
      int byte = (row * 256 + kt * 64 + (lane >> 4) * 16) ^ ((row & 7) << 4);
      a[r] = *reinterpret_cast<const short8v*>(
          reinterpret_cast<const char*>(H1) + byte);
    }
#pragma unroll
    for (int c = 0; c < 2; ++c) {
      int col = colbase + c * 16 + (lane & 15);
      b[c] = *reinterpret_cast<const short8v*>(
          reinterpret_cast<const char*>(Wt1) + col * 256 + kt * 64 +
          (lane >> 4) * 16);
    }
#pragma unroll
    for (int r = 0; r < 2; ++r)
#pragma unroll
      for (int c = 0; c < 2; ++c)
        acc[r][c] = __builtin_amdgcn_mfma_f32_16x16x32_bf16(a[r], b[c],
                                                            acc[r][c], 0, 0, 0);
  }
#pragma unroll
  for (int r = 0; r < 2; ++r)
#pragma unroll
    for (int c = 0; c < 2; ++c)
#pragma unroll
      for (int q2 = 0; q2 < 4; ++q2) {
        int row = r * 16 + (lane >> 4) * 4 + q2;
        int col = colbase + c * 16 + (lane & 15);
        float v = fmaxf(acc[r][c][q2] + bias1[c], 0.f);
        int byte = (row * 256 + col * 2) ^ ((row & 7) << 4);
        *reinterpret_cast<unsigned short*>(reinterpret_cast<char*>(H2) + byte) =
            f2bf(v);
      }
  __syncthreads();

  // ---- phase 3: GEMM2 (H2 @ Wt2 + b2) -> out ----
  f32x4 acc2[2][2] = {};
#pragma unroll
  for (int kt = 0; kt < 4; ++kt) {
    short8v a[2], b[2];
#pragma unroll
    for (int r = 0; r < 2; ++r) {
      int row = r * 16 + (lane & 15);
      int byte = (row * 256 + kt * 64 + (lane >> 4) * 16) ^ ((row & 7) << 4);
      a[r] = *reinterpret_cast<const short8v*>(
          reinterpret_cast<const char*>(H2) + byte);
    }
#pragma unroll
    for (int c = 0; c < 2; ++c) {
      int col = colbase + c * 16 + (lane & 15);
      b[c] = *reinterpret_cast<const short8v*>(
          reinterpret_cast<const char*>(Wt2) + col * 256 + kt * 64 +
          (lane >> 4) * 16);
    }
#pragma unroll
    for (int r = 0; r < 2; ++r)
#pragma unroll
      for (int c = 0; c < 2; ++c)
        acc2[r][c] = __builtin_amdgcn_mfma_f32_16x16x32_bf16(
            a[r], b[c], acc2[r][c], 0, 0, 0);
  }
#pragma unroll
  for (int r = 0; r < 2; ++r)
#pragma unroll
    for (int c = 0; c < 2; ++c)
#pragma unroll
      for (int q2 = 0; q2 < 4; ++q2) {
        int row = base + r * 16 + (lane >> 4) * 4 + q2;
        if (row < N_NODES) {
          int col = colbase + c * 16 + (lane & 15);
          out[(size_t)row * HIDDEN + col] = acc2[r][c][q2] + bias2[c];
        }
      }
}

// ---------------- Tier-C fallback (round-2 proven) ----------------
__global__ __launch_bounds__(256) void scatter_kernel(
    const int* __restrict__ ei, const float* __restrict__ x,
    float* __restrict__ agg) {
  long long gid = (long long)blockIdx.x * blockDim.x + threadIdx.x;
  int e = (int)(gid >> 5);
  if (e >= N_EDGES) return;
  int sub = ((int)gid & 31) * 4;
  int src = ei[e];
  int dst = ei[N_EDGES + e];
  const float4 v = *reinterpret_cast<const float4*>(x + src * HIDDEN + sub);
  float* p = agg + dst * HIDDEN + sub;
  atomicAdd(p + 0, v.x);
  atomicAdd(p + 1, v.y);
  atomicAdd(p + 2, v.z);
  atomicAdd(p + 3, v.w);
}

__global__ __launch_bounds__(512) void mlp_kernel(
    const float* __restrict__ x, float* __restrict__ io,
    const float* __restrict__ W1, const float* __restrict__ b1,
    const float* __restrict__ W2, const float* __restrict__ b2) {
  __shared__ float W1s[HIDDEN * HIDDEN];
  __shared__ float W2s[HIDDEN * HIDDEN];

  const int tid = threadIdx.x;
#pragma unroll
  for (int i = 0; i < 8; ++i) {
    int idx = (i * 512 + tid) * 4;
    *reinterpret_cast<float4*>(W1s + idx) =
        *reinterpret_cast<const float4*>(W1 + idx);
    *reinterpret_cast<float4*>(W2s + idx) =
        *reinterpret_cast<const float4*>(W2 + idx);
  }

  const int lane = tid & 63;
  const int wave = tid >> 6;
  const int c0 = 2 * lane, c1 = 2 * lane + 1;

  const float m0 = col_mask(c0);
  const float m1 = col_mask(c1);
  const float bb1x = b1[c0], bb1y = b1[c1];
  const float bb2x = b2[c0], bb2y = b2[c1];

  __syncthreads();

  const int gwave = blockIdx.x * 8 + wave;
  const int nwaves = gridDim.x * 8;

  for (int pr = gwave; pr < N_NODES / 2; pr += nwaves) {
    const int baseA = (2 * pr) * HIDDEN;
    const int baseB = baseA + HIDDEN;

    float2 xA = *reinterpret_cast<const float2*>(x + baseA + c0);
    float2 gA = *reinterpret_cast<const float2*>(io + baseA + c0);
    float2 xB = *reinterpret_cast<const float2*>(x + baseB + c0);
    float2 gB = *reinterpret_cast<const float2*>(io + baseB + c0);

    float hA0 = m0 * (xA.x + gA.x), hA1 = m1 * (xA.y + gA.y);
    float hB0 = m0 * (xB.x + gB.x), hB1 = m1 * (xB.y + gB.y);

    float aA0 = bb1x, aA1 = bb1y, aB0 = bb1x, aB1 = bb1y;
#pragma unroll
    for (int k = 0; k < HIDDEN; ++k) {
      const int sl = k >> 1;
      float hkA = (k & 1) ? rlane(hA1, sl) : rlane(hA0, sl);
      float hkB = (k & 1) ? rlane(hB1, sl) : rlane(hB0, sl);
      float2 w = *reinterpret_cast<const float2*>(W1s + k * HIDDEN + c0);
      aA0 = fmaf(hkA, w.x, aA0);
      aA1 = fmaf(hkA, w.y, aA1);
      aB0 = fmaf(hkB, w.x, aB0);
      aB1 = fmaf(hkB, w.y, aB1);
    }
    aA0 = fmaxf(aA0, 0.0f); aA1 = fmaxf(aA1, 0.0f);
    aB0 = fmaxf(aB0, 0.0f); aB1 = fmaxf(aB1, 0.0f);

    float oA0 = bb2x, oA1 = bb2y, oB0 = bb2x, oB1 = bb2y;
#pragma unroll
    for (int k = 0; k < HIDDEN; ++k) {
      const int sl = k >> 1;
      float hkA = (k & 1) ? rlane(aA1, sl) : rlane(aA0, sl);
      float hkB = (k & 1) ? rlane(aB1, sl) : rlane(aB0, sl);
      float2 w = *reinterpret_cast<const float2*>(W2s + k * HIDDEN + c0);
      oA0 = fmaf(hkA, w.x, oA0);
      oA1 = fmaf(hkA, w.y, oA1);
      oB0 = fmaf(hkB, w.x, oB0);
      oB1 = fmaf(hkB, w.y, oB1);
    }

    *reinterpret_cast<float2*>(io + baseA + c0) = make_float2(oA0, oA1);
    *reinterpret_cast<float2*>(io + baseB + c0) = make_float2(oB0, oB1);
  }
}

extern "C" void kernel_launch(void* const* d_in, const int* in_sizes, int n_in,
                              void* d_out, int out_size, void* d_ws,
                              size_t ws_size, hipStream_t stream) {
  (void)in_sizes; (void)n_in; (void)out_size;
  const float* x  = (const float*)d_in[0];
  const int*   ei = (const int*)d_in[1];
  const float* W1 = (const float*)d_in[2];
  const float* b1 = (const float*)d_in[3];
  const float* W2 = (const float*)d_in[4];
  const float* b2 = (const float*)d_in[5];
  float* out = (float*)d_out;

  // ws layout: [ints: deg N | offs N+1 | pos N | bsum NB | bpre NB] pad16
  //            [u16: csr E_PAD_MAX] [u16: Wt1 16384 | Wt2 16384]
  //            [u16: xb (N_NODES+1)*HIDDEN]
  const size_t int_bytes = (size_t)(N_NODES + (N_NODES + 1) + N_NODES + 2 * NB) * 4;
  const size_t int_pad   = (int_bytes + 15) & ~(size_t)15;
  const size_t csr_bytes = (size_t)E_PAD_MAX * 2;
  const size_t wt_bytes  = 2 * (size_t)HIDDEN * HIDDEN * 2;
  const size_t xb_bytes  = (size_t)(N_NODES + 1) * HIDDEN * 2;
  const size_t need = int_pad + csr_bytes + wt_bytes + xb_bytes;

  if (ws_size >= need) {
    char* wsb = (char*)d_ws;
    int* deg  = (int*)wsb;
    int* offs = deg + N_NODES;
    int* pos  = offs + N_NODES + 1;
    int* bsum = pos + N_NODES;
    int* bpre = bsum + NB;
    unsigned short* csr = (unsigned short*)(wsb + int_pad);
    unsigned short* Wt1 = (unsigned short*)(wsb + int_pad + csr_bytes);
    unsigned short* Wt2 = Wt1 + HIDDEN * HIDDEN;
    unsigned short* xb  = Wt2 + HIDDEN * HIDDEN;

    hipMemsetAsync(deg, 0, (size_t)N_NODES * 4, stream);
    const int nprep = (N_NODES * HIDDEN / 8 + 255) / 256;  // 3125
    prep_kernel<<<nprep, 256, 0, stream>>>(x, W1, W2, ei, xb, Wt1, Wt2, deg);
    scanA_kernel<<<NB, 256, 0, stream>>>(deg, bsum);
    scanB_kernel<<<1, 256, 0, stream>>>(bsum, bpre, offs);
    scanC_kernel<<<NB, 256, 0, stream>>>(deg, bpre, offs, pos, csr);
    fill_kernel<<<(N_EDGES + 255) / 256, 256, 0, stream>>>(ei, pos, csr);
    fused_xb_kernel<<<NTILES, 256, 0, stream>>>(offs, csr, xb, Wt1, Wt2, b1,
                                                b2, out);
  } else {
    // Tier C: atomic scatter + rlane MLP (proven, slow).
    hipMemsetAsync(out, 0, (size_t)N_NODES * HIDDEN * sizeof(float), stream);
    const long long total = (long long)N_EDGES * 32;
    scatter_kernel<<<(int)((total + 255) / 256), 256, 0, stream>>>(ei, x, out);
    mlp_kernel<<<256, 512, 0, stream>>>(x, out, W1, b1, W2, b2);
  }
}